// Round 5
// baseline (11704.375 us; speedup 1.0000x reference)
//
#include <hip/hip_runtime.h>

// TopDownTreeLSTM on MI355X — round 10: INSTRUMENTATION (keeps r8 kernel).
// r5/r7/r8 all ~1480us across different sync schemes; r9 (confounded) 2.4x
// worse. Four rounds of missed predictions => measure, don't guess.
//   k_probe: 1 block, per-level dependent chain of 4096 v_fma (16384 cyc
//            = 6.83us @2.4GHz) -> top-5 table duration encodes maxd.
//   k_diag:  r8's k_tree2 with waits stripped, run on pre-zeroed VALID C/Hb
//            before poisoning -> pure machinery time, recovered from dur_us.
// Real pipeline (r8 k_tree2, unchanged) still runs and is what's verified.

#define NN 32768
#define DD 256
#define GP 1024
#define OFFCAP 4096
#define SENT_C 0x7FC00001u   // f32 NaN payload: real c is always finite
#define SENT_H 0xFFFFFFFFu   // bf16 -NaN pair: real h = sig*tanh in (-1,1)

typedef __attribute__((ext_vector_type(8))) short short8;
typedef __attribute__((ext_vector_type(4))) float float4_;
typedef __attribute__((ext_vector_type(4))) unsigned uint4_;

static __device__ __forceinline__ unsigned short f2bf(float f) {
    unsigned u = __builtin_bit_cast(unsigned, f);
    unsigned r = u + 0x7FFFu + ((u >> 16) & 1u);
    return (unsigned short)(r >> 16);
}
static __device__ __forceinline__ float bf2f(unsigned short u) {
    unsigned v = ((unsigned)u) << 16;
    return __builtin_bit_cast(float, v);
}
static __device__ __forceinline__ float sigf(float x) { return 1.0f / (1.0f + __expf(-x)); }
static __device__ __forceinline__ float tanh_(float x) { return 1.0f - 2.0f / (__expf(2.0f * x) + 1.0f); }

// ---- scheduling-scratch init (must precede k_hist) ----
__global__ void k_init_sched(int* cnt, int* cur, int* maxd) {
    int g = blockIdx.x * 256 + threadIdx.x;
    if (g < NN + 2) { cnt[g] = 0; cur[g] = 0; }
    if (g == 0) maxd[0] = 0;
}

// ---- zero C/Hb (valid, non-sentinel) for the machinery replica ----
__global__ void k_zero(float* C, unsigned* HbU) {
    const int g = blockIdx.x * 256 + threadIdx.x;   // grid 2048 x 256
    const uint4_ z = (uint4_){0u, 0u, 0u, 0u};
    uint4_* Cu = (uint4_*)C;
    uint4_* Hu = (uint4_*)HbU;
    #pragma unroll
    for (int k = 0; k < 4; ++k) Cu[(size_t)g + (size_t)k * 524288] = z;
    #pragma unroll
    for (int k = 0; k < 2; ++k) Hu[(size_t)g + (size_t)k * 524288] = z;
}

// ---- poison C/Hb with sentinels for the real dataflow run ----
__global__ void k_poison(float* C, unsigned* HbU) {
    const int g = blockIdx.x * 256 + threadIdx.x;   // grid 2048 x 256
    const uint4_ sc = (uint4_){SENT_C, SENT_C, SENT_C, SENT_C};
    const uint4_ sh = (uint4_){SENT_H, SENT_H, SENT_H, SENT_H};
    uint4_* Cu = (uint4_*)C;
    uint4_* Hu = (uint4_*)HbU;
    #pragma unroll
    for (int k = 0; k < 4; ++k) Cu[(size_t)g + (size_t)k * 524288] = sc;
    #pragma unroll
    for (int k = 0; k < 2; ++k) Hu[(size_t)g + (size_t)k * 524288] = sh;
}

// ---- depth probe: duration = maxd * 6.83us (@2.4GHz). Read from top-5. ----
__global__ void k_probe(const int* __restrict__ maxd_g, float* sink) {
    const int maxd = maxd_g[0];
    float x = 1.0f + threadIdx.x * 1e-7f;
    float a = 1.0000001f, b = 1e-9f;
    #pragma unroll 1
    for (int d = 0; d < maxd; ++d) {
        #pragma unroll 1
        for (int k = 0; k < 1024; ++k) {
            asm volatile("v_fma_f32 %0, %0, %1, %2\n\t"
                         "v_fma_f32 %0, %0, %1, %2\n\t"
                         "v_fma_f32 %0, %0, %1, %2\n\t"
                         "v_fma_f32 %0, %0, %1, %2"
                         : "+v"(x) : "v"(a), "v"(b));
        }
    }
    if (threadIdx.x == 0) sink[0] = x;
}

__global__ void k_root(const float* __restrict__ X, const float* __restrict__ state,
                       const float* __restrict__ rootW, const float* __restrict__ rootb,
                       const int* __restrict__ idx,
                       unsigned short* __restrict__ Hb, float* __restrict__ C) {
    const int t = threadIdx.x;
    const int row = idx[0];
    const float4_* xr = (const float4_*)(X + (size_t)row * DD);
    const float4_* wr = (const float4_*)(rootW + (size_t)t * DD);
    float acc = rootb[t];
    for (int k = 0; k < DD / 4; ++k) {
        float4_ a = xr[k], b = wr[k];
        acc += a[0] * b[0] + a[1] * b[1] + a[2] * b[2] + a[3] * b[3];
    }
    Hb[t] = f2bf(tanh_(acc));
    C[t] = state[t];
}

__global__ void k_dep_init(const int* __restrict__ parents, int* dep, int* jmp) {
    int i = blockIdx.x * 256 + threadIdx.x;
    if (i >= NN) return;
    dep[i] = (i == 0) ? 0 : 1;
    jmp[i] = (i == 0) ? 0 : parents[i];
}

__global__ void k_dep_step(const int* __restrict__ depA, const int* __restrict__ jmpA,
                           int* __restrict__ depB, int* __restrict__ jmpB) {
    int i = blockIdx.x * 256 + threadIdx.x;
    if (i >= NN) return;
    int j = jmpA[i];
    depB[i] = depA[i] + depA[j];
    jmpB[i] = jmpA[j];
}

__global__ void k_hist(const int* __restrict__ dep, int* cnt, int* maxd) {
    int i = blockIdx.x * 256 + threadIdx.x;
    if (i >= NN) return;
    int d = dep[i];
    atomicAdd(&cnt[d], 1);
    atomicMax(&maxd[0], d);
}

__global__ void k_scan(const int* __restrict__ cnt, int* __restrict__ off) {
    __shared__ int sums[256];
    const int tid = threadIdx.x;
    const int base = tid * 128;
    int s = 0;
    for (int k = 0; k < 128; ++k) s += cnt[base + k];
    sums[tid] = s;
    __syncthreads();
    if (tid == 0) {
        int run = 0;
        for (int t = 0; t < 256; ++t) { int tmp = sums[t]; sums[t] = run; run += tmp; }
    }
    __syncthreads();
    int run = sums[tid];
    for (int k = 0; k < 128; ++k) { off[base + k] = run; run += cnt[base + k]; }
    if (tid == 255) off[NN] = run;
}

__global__ void k_scatter(const int* __restrict__ dep, const int* __restrict__ off,
                          int* cur, int* __restrict__ lev) {
    int i = blockIdx.x * 256 + threadIdx.x;
    if (i >= NN) return;
    int d = dep[i];
    int pos = off[d] + atomicAdd(&cur[d], 1);
    lev[pos] = i;
}

// Throughput GEMM: Gpre[n][g] = sum_k X[idx[n]][k]*Wih[g][k] + bih[g] + bhh[g], bf16 out.
__global__ __launch_bounds__(256, 1) void k_gx(
    const float* __restrict__ X, const float* __restrict__ Wih,
    const float* __restrict__ bih, const float* __restrict__ bhh,
    const int* __restrict__ idx, unsigned short* __restrict__ Gp) {
    __shared__ __align__(16) short bw_s[128 * 264];
    __shared__ float bias_s[128];
    const int tid = threadIdx.x;
    const int w = tid >> 6, l = tid & 63;
    const int lanelo = l & 15, quad = l >> 4;

    short8 a[2][8];
    #pragma unroll
    for (int ti = 0; ti < 2; ++ti) {
        int n = (blockIdx.x * 8 + w * 2 + ti) * 16 + lanelo;
        int row = idx[n];
        const float* xp = X + (size_t)row * DD + quad * 8;
        #pragma unroll
        for (int ks = 0; ks < 8; ++ks) {
            float4_ x0 = *(const float4_*)(xp + ks * 32);
            float4_ x1 = *(const float4_*)(xp + ks * 32 + 4);
            short8 s;
            s[0] = f2bf(x0[0]); s[1] = f2bf(x0[1]); s[2] = f2bf(x0[2]); s[3] = f2bf(x0[3]);
            s[4] = f2bf(x1[0]); s[5] = f2bf(x1[1]); s[6] = f2bf(x1[2]); s[7] = f2bf(x1[3]);
            a[ti][ks] = s;
        }
    }
    for (int gc = 0; gc < 8; ++gc) {
        __syncthreads();
        for (int e = tid; e < 128 * 64; e += 256) {
            int r = e >> 6, c4 = (e & 63) * 4;
            float4_ b = *(const float4_*)(Wih + (size_t)(gc * 128 + r) * DD + c4);
            unsigned short* pb = (unsigned short*)&bw_s[r * 264 + c4];
            pb[0] = f2bf(b[0]); pb[1] = f2bf(b[1]); pb[2] = f2bf(b[2]); pb[3] = f2bf(b[3]);
        }
        if (tid < 128) bias_s[tid] = bih[gc * 128 + tid] + bhh[gc * 128 + tid];
        __syncthreads();
        #pragma unroll
        for (int ntl = 0; ntl < 8; ++ntl) {
            float4_ acc0 = (float4_){0.f, 0.f, 0.f, 0.f};
            float4_ acc1 = (float4_){0.f, 0.f, 0.f, 0.f};
            #pragma unroll
            for (int ks = 0; ks < 8; ++ks) {
                short8 bf = *(const short8*)&bw_s[(ntl * 16 + lanelo) * 264 + ks * 32 + quad * 8];
                acc0 = __builtin_amdgcn_mfma_f32_16x16x32_bf16(a[0][ks], bf, acc0, 0, 0, 0);
                acc1 = __builtin_amdgcn_mfma_f32_16x16x32_bf16(a[1][ks], bf, acc1, 0, 0, 0);
            }
            float bia = bias_s[ntl * 16 + lanelo];
            int g = gc * 128 + ntl * 16 + lanelo;
            int nb0 = (blockIdx.x * 8 + w * 2) * 16 + quad * 4;
            #pragma unroll
            for (int r = 0; r < 4; ++r) {
                Gp[(size_t)(nb0 + r) * GP + g] = f2bf(acc0[r] + bia);
                Gp[(size_t)(nb0 + 16 + r) * GP + g] = f2bf(acc1[r] + bia);
            }
        }
    }
}

// ---- r8's k_tree2, byte-identical ----
__global__ __launch_bounds__(256, 1) void k_tree2(
    const float* __restrict__ Whh,
    const int* __restrict__ parents,
    const int* __restrict__ off, const int* __restrict__ lev, const int* __restrict__ maxd_g,
    const unsigned short* __restrict__ Gp,
    unsigned short* __restrict__ Hb, float* __restrict__ C) {

    __shared__ __align__(16) short w_s[128 * 264];   // W_hh slice, bf16, K=256
    __shared__ __align__(16) short A_s[16 * 264];    // parent H rows, bf16
    __shared__ __align__(16) float G_s[16 * 128];    // Gpre tile (this block's 128 gate cols)
    __shared__ __align__(16) float R_s[16 * 132];    // recurrent gate partials
    __shared__ int off_s[OFFCAP];                    // level offsets (LDS-rate)
    __shared__ int nd_s[16], par_s[16];

    const int tid = threadIdx.x;
    const int j = blockIdx.x & 7, grp = blockIdx.x >> 3;
    const int w = tid >> 6, l = tid & 63;
    const int lanelo = l & 15, quad = l >> 4;

    for (int e = tid; e < 128 * 64; e += 256) {
        int r = e >> 6, c4 = (e & 63) * 4;
        int G = ((r >> 5) * 256) + j * 32 + (r & 31);
        float4_ b = *(const float4_*)(Whh + (size_t)G * DD + c4);
        unsigned short* pb = (unsigned short*)&w_s[r * 264 + c4];
        pb[0] = f2bf(b[0]); pb[1] = f2bf(b[1]); pb[2] = f2bf(b[2]); pb[3] = f2bf(b[3]);
    }
    const int maxd = maxd_g[0];
    const int staged = (maxd + 2 < OFFCAP) ? (maxd + 2) : OFFCAP;
    for (int e = tid; e < staged; e += 256) off_s[e] = off[e];
    __syncthreads();

    #define OFFS(i) (((i) < staged) ? off_s[(i)] : off[(i)])

    const unsigned* HbU = (const unsigned*)Hb;
    int pn_node = -1, pn_par = 0;
    bool pn_valid = false;

    int lo = OFFS(1);
    for (int d = 1; d <= maxd; ++d) {
        const int hi = OFFS(d + 1);
        const int tiles = (hi - lo + 15) >> 4;
        for (int t = grp; t < tiles; t += 32) {
            const int base = lo + t * 16;
            if (tid < 16) {
                if (pn_valid) {
                    nd_s[tid] = pn_node; par_s[tid] = pn_par;
                } else {
                    int node = -1, p = 0;
                    if (base + tid < hi) { node = lev[base + tid]; p = parents[node]; }
                    nd_s[tid] = node; par_s[tid] = p;
                }
            }
            pn_valid = false;
            __syncthreads();
            {
                int m = tid >> 4, q8 = (tid & 15) * 8;
                int seg = q8 >> 5, cc = q8 & 31;
                float4_ g01 = (float4_){0.f, 0.f, 0.f, 0.f};
                float4_ g23 = (float4_){0.f, 0.f, 0.f, 0.f};
                if (nd_s[m] >= 0) {
                    const unsigned short* gp =
                        Gp + (size_t)nd_s[m] * GP + seg * 256 + j * 32 + cc;
                    short8 gv = *(const short8*)gp;
                    g01[0] = bf2f(gv[0]); g01[1] = bf2f(gv[1]); g01[2] = bf2f(gv[2]); g01[3] = bf2f(gv[3]);
                    g23[0] = bf2f(gv[4]); g23[1] = bf2f(gv[5]); g23[2] = bf2f(gv[6]); g23[3] = bf2f(gv[7]);
                }
                *(float4_*)&G_s[m * 128 + q8] = g01;
                *(float4_*)&G_s[m * 128 + q8 + 4] = g23;
            }
            {
                int nt_base = -1, nt_hi = hi;
                if (t + 32 < tiles) {
                    nt_base = lo + (t + 32) * 16;
                } else if (d < maxd) {
                    const int hi2 = OFFS(d + 2);
                    const int tiles2 = (hi2 - hi + 15) >> 4;
                    if (grp < tiles2) { nt_base = hi + grp * 16; nt_hi = hi2; }
                }
                if (nt_base >= 0) {
                    if (tid < 16) {
                        int node = -1, p = 0;
                        if (nt_base + tid < nt_hi) { node = lev[nt_base + tid]; p = parents[node]; }
                        pn_node = node; pn_par = p;
                    }
                    pn_valid = true;
                }
            }
            const int m0 = tid >> 5, c0 = tid & 31, col = j * 32 + c0;
            float* cpp0 = &C[(size_t)par_s[m0] * DD + col];
            float* cpp1 = &C[(size_t)par_s[m0 + 8] * DD + col];
            float cp0 = __hip_atomic_load(cpp0, __ATOMIC_RELAXED, __HIP_MEMORY_SCOPE_AGENT);
            float cp1 = __hip_atomic_load(cpp1, __ATOMIC_RELAXED, __HIP_MEMORY_SCOPE_AGENT);
            unsigned hv[8];
            bool ok = true;
            #pragma unroll
            for (int k2 = 0; k2 < 8; ++k2) {
                const int e = tid + k2 * 256, m = e >> 7, cu = e & 127;
                hv[k2] = (nd_s[m] >= 0)
                    ? __hip_atomic_load(&HbU[(size_t)par_s[m] * 128 + cu],
                                        __ATOMIC_RELAXED, __HIP_MEMORY_SCOPE_AGENT)
                    : 0u;
                if (nd_s[m] >= 0 && hv[k2] == SENT_H) ok = false;
            }
            if (nd_s[m0] >= 0 && __builtin_bit_cast(unsigned, cp0) == SENT_C) ok = false;
            if (nd_s[m0 + 8] >= 0 && __builtin_bit_cast(unsigned, cp1) == SENT_C) ok = false;
            if (!__syncthreads_and(ok ? 1 : 0)) {
                if (tid < 64) {
                    const int m = tid & 15;
                    const bool act = (tid < 16) && (nd_s[m] >= 0);
                    const unsigned* sp = &HbU[(size_t)par_s[m] * 128 + j * 16];
                    bool miss = act && (__hip_atomic_load(sp, __ATOMIC_RELAXED,
                                                          __HIP_MEMORY_SCOPE_AGENT) == SENT_H);
                    while (__any(miss ? 1 : 0))
                        miss = act && (__hip_atomic_load(sp, __ATOMIC_RELAXED,
                                                         __HIP_MEMORY_SCOPE_AGENT) == SENT_H);
                }
                __syncthreads();
                if (nd_s[m0] >= 0)
                    while (__builtin_bit_cast(unsigned, cp0) == SENT_C) {
                        __builtin_amdgcn_s_sleep(1);
                        cp0 = __hip_atomic_load(cpp0, __ATOMIC_RELAXED, __HIP_MEMORY_SCOPE_AGENT);
                    }
                if (nd_s[m0 + 8] >= 0)
                    while (__builtin_bit_cast(unsigned, cp1) == SENT_C) {
                        __builtin_amdgcn_s_sleep(1);
                        cp1 = __hip_atomic_load(cpp1, __ATOMIC_RELAXED, __HIP_MEMORY_SCOPE_AGENT);
                    }
                #pragma unroll
                for (int k2 = 0; k2 < 8; ++k2) {
                    const int e = tid + k2 * 256, m = e >> 7, cu = e & 127;
                    if (nd_s[m] >= 0)
                        while (hv[k2] == SENT_H) {
                            __builtin_amdgcn_s_sleep(1);
                            hv[k2] = __hip_atomic_load(&HbU[(size_t)par_s[m] * 128 + cu],
                                                       __ATOMIC_RELAXED, __HIP_MEMORY_SCOPE_AGENT);
                        }
                }
            }
            #pragma unroll
            for (int k2 = 0; k2 < 8; ++k2) {
                const int e = tid + k2 * 256, m = e >> 7, cu = e & 127;
                *(unsigned*)&A_s[m * 264 + cu * 2] = hv[k2];
            }
            __syncthreads();
            {
                short8 af[8];
                #pragma unroll
                for (int ks = 0; ks < 8; ++ks)
                    af[ks] = *(const short8*)&A_s[lanelo * 264 + ks * 32 + quad * 8];
                #pragma unroll
                for (int ti = 0; ti < 2; ++ti) {
                    int ntl = w * 2 + ti;
                    float4_ acc = (float4_){0.f, 0.f, 0.f, 0.f};
                    #pragma unroll
                    for (int ks = 0; ks < 8; ++ks) {
                        short8 bf = *(const short8*)&w_s[(ntl * 16 + lanelo) * 264 + ks * 32 + quad * 8];
                        acc = __builtin_amdgcn_mfma_f32_16x16x32_bf16(af[ks], bf, acc, 0, 0, 0);
                    }
                    #pragma unroll
                    for (int r = 0; r < 4; ++r)
                        R_s[(quad * 4 + r) * 132 + ntl * 16 + lanelo] = acc[r];
                }
            }
            __syncthreads();
            {
                #pragma unroll
                for (int pass = 0; pass < 2; ++pass) {
                    int m = m0 + pass * 8;
                    float cp = pass ? cp1 : cp0;
                    float ig = R_s[m * 132 + c0]      + G_s[m * 128 + c0];
                    float fg = R_s[m * 132 + 32 + c0] + G_s[m * 128 + 32 + c0];
                    float gg = R_s[m * 132 + 64 + c0] + G_s[m * 128 + 64 + c0];
                    float og = R_s[m * 132 + 96 + c0] + G_s[m * 128 + 96 + c0];
                    float cn = sigf(fg) * cp + sigf(ig) * tanh_(gg);
                    float hn = sigf(og) * tanh_(cn);
                    int node = nd_s[m];
                    unsigned short hs = f2bf(hn);
                    unsigned pair = ((unsigned)hs) |
                                    (((unsigned)(unsigned short)__shfl_down((int)hs, 1)) << 16);
                    if (node >= 0) {
                        __hip_atomic_store(&C[(size_t)node * DD + col], cn,
                                           __ATOMIC_RELAXED, __HIP_MEMORY_SCOPE_AGENT);
                        if ((c0 & 1) == 0)
                            __hip_atomic_store(&((unsigned*)Hb)[(size_t)node * 128 + (col >> 1)],
                                               pair, __ATOMIC_RELAXED, __HIP_MEMORY_SCOPE_AGENT);
                    }
                }
            }
            __builtin_amdgcn_fence(__ATOMIC_RELEASE, "workgroup");
            __syncthreads();
        }
        lo = hi;
    }
    #undef OFFS
}

// ---- machinery replica: identical schedule/ops, NO waiting (valid inputs) ----
__global__ __launch_bounds__(256, 1) void k_diag(
    const float* __restrict__ Whh,
    const int* __restrict__ parents,
    const int* __restrict__ off, const int* __restrict__ lev, const int* __restrict__ maxd_g,
    const unsigned short* __restrict__ Gp,
    unsigned short* __restrict__ Hb, float* __restrict__ C) {

    __shared__ __align__(16) short w_s[128 * 264];
    __shared__ __align__(16) short A_s[16 * 264];
    __shared__ __align__(16) float G_s[16 * 128];
    __shared__ __align__(16) float R_s[16 * 132];
    __shared__ int off_s[OFFCAP];
    __shared__ int nd_s[16], par_s[16];

    const int tid = threadIdx.x;
    const int j = blockIdx.x & 7, grp = blockIdx.x >> 3;
    const int w = tid >> 6, l = tid & 63;
    const int lanelo = l & 15, quad = l >> 4;

    for (int e = tid; e < 128 * 64; e += 256) {
        int r = e >> 6, c4 = (e & 63) * 4;
        int G = ((r >> 5) * 256) + j * 32 + (r & 31);
        float4_ b = *(const float4_*)(Whh + (size_t)G * DD + c4);
        unsigned short* pb = (unsigned short*)&w_s[r * 264 + c4];
        pb[0] = f2bf(b[0]); pb[1] = f2bf(b[1]); pb[2] = f2bf(b[2]); pb[3] = f2bf(b[3]);
    }
    const int maxd = maxd_g[0];
    const int staged = (maxd + 2 < OFFCAP) ? (maxd + 2) : OFFCAP;
    for (int e = tid; e < staged; e += 256) off_s[e] = off[e];
    __syncthreads();

    #define OFFS(i) (((i) < staged) ? off_s[(i)] : off[(i)])

    const unsigned* HbU = (const unsigned*)Hb;
    int pn_node = -1, pn_par = 0;
    bool pn_valid = false;

    int lo = OFFS(1);
    for (int d = 1; d <= maxd; ++d) {
        const int hi = OFFS(d + 1);
        const int tiles = (hi - lo + 15) >> 4;
        for (int t = grp; t < tiles; t += 32) {
            const int base = lo + t * 16;
            if (tid < 16) {
                if (pn_valid) {
                    nd_s[tid] = pn_node; par_s[tid] = pn_par;
                } else {
                    int node = -1, p = 0;
                    if (base + tid < hi) { node = lev[base + tid]; p = parents[node]; }
                    nd_s[tid] = node; par_s[tid] = p;
                }
            }
            pn_valid = false;
            __syncthreads();
            {
                int m = tid >> 4, q8 = (tid & 15) * 8;
                int seg = q8 >> 5, cc = q8 & 31;
                float4_ g01 = (float4_){0.f, 0.f, 0.f, 0.f};
                float4_ g23 = (float4_){0.f, 0.f, 0.f, 0.f};
                if (nd_s[m] >= 0) {
                    const unsigned short* gp =
                        Gp + (size_t)nd_s[m] * GP + seg * 256 + j * 32 + cc;
                    short8 gv = *(const short8*)gp;
                    g01[0] = bf2f(gv[0]); g01[1] = bf2f(gv[1]); g01[2] = bf2f(gv[2]); g01[3] = bf2f(gv[3]);
                    g23[0] = bf2f(gv[4]); g23[1] = bf2f(gv[5]); g23[2] = bf2f(gv[6]); g23[3] = bf2f(gv[7]);
                }
                *(float4_*)&G_s[m * 128 + q8] = g01;
                *(float4_*)&G_s[m * 128 + q8 + 4] = g23;
            }
            {
                int nt_base = -1, nt_hi = hi;
                if (t + 32 < tiles) {
                    nt_base = lo + (t + 32) * 16;
                } else if (d < maxd) {
                    const int hi2 = OFFS(d + 2);
                    const int tiles2 = (hi2 - hi + 15) >> 4;
                    if (grp < tiles2) { nt_base = hi + grp * 16; nt_hi = hi2; }
                }
                if (nt_base >= 0) {
                    if (tid < 16) {
                        int node = -1, p = 0;
                        if (nt_base + tid < nt_hi) { node = lev[nt_base + tid]; p = parents[node]; }
                        pn_node = node; pn_par = p;
                    }
                    pn_valid = true;
                }
            }
            const int m0 = tid >> 5, c0 = tid & 31, col = j * 32 + c0;
            float* cpp0 = &C[(size_t)par_s[m0] * DD + col];
            float* cpp1 = &C[(size_t)par_s[m0 + 8] * DD + col];
            float cp0 = __hip_atomic_load(cpp0, __ATOMIC_RELAXED, __HIP_MEMORY_SCOPE_AGENT);
            float cp1 = __hip_atomic_load(cpp1, __ATOMIC_RELAXED, __HIP_MEMORY_SCOPE_AGENT);
            unsigned hv[8];
            bool ok = true;
            #pragma unroll
            for (int k2 = 0; k2 < 8; ++k2) {
                const int e = tid + k2 * 256, m = e >> 7, cu = e & 127;
                hv[k2] = (nd_s[m] >= 0)
                    ? __hip_atomic_load(&HbU[(size_t)par_s[m] * 128 + cu],
                                        __ATOMIC_RELAXED, __HIP_MEMORY_SCOPE_AGENT)
                    : 0u;
                if (nd_s[m] >= 0 && hv[k2] == SENT_H) ok = false;
            }
            if (nd_s[m0] >= 0 && __builtin_bit_cast(unsigned, cp0) == SENT_C) ok = false;
            if (nd_s[m0 + 8] >= 0 && __builtin_bit_cast(unsigned, cp1) == SENT_C) ok = false;
            // NO-WAIT: keep the barrier cost, ignore the verdict (inputs valid).
            (void)__syncthreads_and(ok ? 1 : 0);
            #pragma unroll
            for (int k2 = 0; k2 < 8; ++k2) {
                const int e = tid + k2 * 256, m = e >> 7, cu = e & 127;
                *(unsigned*)&A_s[m * 264 + cu * 2] = hv[k2];
            }
            __syncthreads();
            {
                short8 af[8];
                #pragma unroll
                for (int ks = 0; ks < 8; ++ks)
                    af[ks] = *(const short8*)&A_s[lanelo * 264 + ks * 32 + quad * 8];
                #pragma unroll
                for (int ti = 0; ti < 2; ++ti) {
                    int ntl = w * 2 + ti;
                    float4_ acc = (float4_){0.f, 0.f, 0.f, 0.f};
                    #pragma unroll
                    for (int ks = 0; ks < 8; ++ks) {
                        short8 bf = *(const short8*)&w_s[(ntl * 16 + lanelo) * 264 + ks * 32 + quad * 8];
                        acc = __builtin_amdgcn_mfma_f32_16x16x32_bf16(af[ks], bf, acc, 0, 0, 0);
                    }
                    #pragma unroll
                    for (int r = 0; r < 4; ++r)
                        R_s[(quad * 4 + r) * 132 + ntl * 16 + lanelo] = acc[r];
                }
            }
            __syncthreads();
            {
                #pragma unroll
                for (int pass = 0; pass < 2; ++pass) {
                    int m = m0 + pass * 8;
                    float cp = pass ? cp1 : cp0;
                    float ig = R_s[m * 132 + c0]      + G_s[m * 128 + c0];
                    float fg = R_s[m * 132 + 32 + c0] + G_s[m * 128 + 32 + c0];
                    float gg = R_s[m * 132 + 64 + c0] + G_s[m * 128 + 64 + c0];
                    float og = R_s[m * 132 + 96 + c0] + G_s[m * 128 + 96 + c0];
                    float cn = sigf(fg) * cp + sigf(ig) * tanh_(gg);
                    float hn = sigf(og) * tanh_(cn);
                    int node = nd_s[m];
                    unsigned short hs = f2bf(hn);
                    unsigned pair = ((unsigned)hs) |
                                    (((unsigned)(unsigned short)__shfl_down((int)hs, 1)) << 16);
                    if (node >= 0) {
                        __hip_atomic_store(&C[(size_t)node * DD + col], cn,
                                           __ATOMIC_RELAXED, __HIP_MEMORY_SCOPE_AGENT);
                        if ((c0 & 1) == 0)
                            __hip_atomic_store(&((unsigned*)Hb)[(size_t)node * 128 + (col >> 1)],
                                               pair, __ATOMIC_RELAXED, __HIP_MEMORY_SCOPE_AGENT);
                    }
                }
            }
            __builtin_amdgcn_fence(__ATOMIC_RELEASE, "workgroup");
            __syncthreads();
        }
        lo = hi;
    }
    #undef OFFS
}

__global__ void k_out(const unsigned short* __restrict__ Hb, const float* __restrict__ C,
                      const int* __restrict__ idx, float* __restrict__ out) {
    const int b = blockIdx.x, t = threadIdx.x;
    if (b < NN) {
        int drow = idx[b];
        out[512 + (size_t)drow * DD + t] = bf2f(Hb[(size_t)b * DD + t]);
    } else {
        out[t] = C[t];
        out[DD + t] = bf2f(Hb[t]);
    }
}

extern "C" void kernel_launch(void* const* d_in, const int* in_sizes, int n_in,
                              void* d_out, int out_size, void* d_ws, size_t ws_size,
                              hipStream_t stream) {
    const float* X     = (const float*)d_in[0];
    const float* state = (const float*)d_in[1];
    const float* rootW = (const float*)d_in[2];
    const float* rootb = (const float*)d_in[3];
    const float* Wih   = (const float*)d_in[4];
    const float* Whh   = (const float*)d_in[5];
    const float* bih   = (const float*)d_in[6];
    const float* bhh   = (const float*)d_in[7];
    const int* parents = (const int*)d_in[8];
    const int* idx     = (const int*)d_in[9];

    float* C           = (float*)d_ws;                                   // 32 MiB
    unsigned short* Hb = (unsigned short*)(C + (size_t)NN * DD);         // 16 MiB
    unsigned short* Gp = Hb + (size_t)NN * DD;                           // 64 MiB
    int* ip            = (int*)(Gp + (size_t)NN * GP);
    int* depA = ip;            ip += NN;
    int* jmpA = ip;            ip += NN;
    int* depB = ip;            ip += NN;
    int* jmpB = ip;            ip += NN;
    int* cnt  = ip;            ip += NN + 2;
    int* off  = ip;            ip += NN + 2;
    int* cur  = ip;            ip += NN + 2;
    int* lev  = ip;            ip += NN;
    int* maxd = ip;            ip += 8;
    float* out = (float*)d_out;

    // scheduling metadata
    k_init_sched<<<dim3(129), dim3(256), 0, stream>>>(cnt, cur, maxd);
    k_dep_init<<<dim3(128), dim3(256), 0, stream>>>(parents, depA, jmpA);
    int* dA = depA; int* jA = jmpA; int* dB = depB; int* jB = jmpB;
    for (int it = 0; it < 15; ++it) {
        k_dep_step<<<dim3(128), dim3(256), 0, stream>>>(dA, jA, dB, jB);
        int* tp;
        tp = dA; dA = dB; dB = tp;
        tp = jA; jA = jB; jB = tp;
    }
    k_hist<<<dim3(128), dim3(256), 0, stream>>>(dA, cnt, maxd);
    k_scan<<<dim3(1), dim3(256), 0, stream>>>(cnt, off);
    k_scatter<<<dim3(128), dim3(256), 0, stream>>>(dA, off, cur, lev);

    k_gx<<<dim3(256), dim3(256), 0, stream>>>(X, Wih, bih, bhh, idx, Gp);

    // --- instrumentation: machinery replica on valid (zeroed) state ---
    k_zero<<<dim3(2048), dim3(256), 0, stream>>>(C, (unsigned*)Hb);
    k_diag<<<dim3(256), dim3(256), 0, stream>>>(Whh, parents, off, lev, maxd, Gp, Hb, C);
    // --- instrumentation: depth probe (duration = maxd * ~6.8us) ---
    k_probe<<<dim3(1), dim3(64), 0, stream>>>(maxd, (float*)(maxd + 2));

    // --- real dataflow run ---
    k_poison<<<dim3(2048), dim3(256), 0, stream>>>(C, (unsigned*)Hb);
    k_root<<<dim3(1), dim3(256), 0, stream>>>(X, state, rootW, rootb, idx, Hb, C);
    k_tree2<<<dim3(256), dim3(256), 0, stream>>>(Whh, parents, off, lev, maxd, Gp, Hb, C);
    k_out<<<dim3(NN + 1), dim3(256), 0, stream>>>(Hb, C, idx, out);
}

// Round 7
// 5470.021 us; speedup vs baseline: 2.1397x; 2.1397x over previous
//
#include <hip/hip_runtime.h>

// TopDownTreeLSTM on MI355X — round 12: r11 (per-wave engines) + restored
// producer drain. r11's only semantic novelty vs verified configs was
// removing the vmcnt drain after stores; if a dirty line can sit in a write
// buffer until the wave forces a drain, consumers livelock -> watchdog ->
// container failure (observed: "failed twice"). r12 re-adds the one-line
// s_waitcnt vmcnt(0) (r5-r9 proven) and changes NOTHING else, cleanly
// measuring the wave-engine idea: 1024 independent 64-lane engines, zero
// LDS/barriers in the loop, W_hh in 64 VGPRs/wave, parent H loaded per-lane
// in MFMA fragment layout (the loads ARE the poll), elementwise in regs.

#define NN 32768
#define DD 256
#define GP 1024
#define SENT_C 0x7FC00001u   // f32 NaN payload: real c is always finite
#define SENT_H 0xFFFFFFFFu   // bf16 -NaN pair: real h in (-1,1)

typedef __attribute__((ext_vector_type(8))) short short8;
typedef __attribute__((ext_vector_type(4))) float float4_;
typedef __attribute__((ext_vector_type(4))) unsigned uint4_;

#define ATL(p) __hip_atomic_load((p), __ATOMIC_RELAXED, __HIP_MEMORY_SCOPE_AGENT)
#define ATS(p, v) __hip_atomic_store((p), (v), __ATOMIC_RELAXED, __HIP_MEMORY_SCOPE_AGENT)

static __device__ __forceinline__ unsigned short f2bf(float f) {
    unsigned u = __builtin_bit_cast(unsigned, f);
    unsigned r = u + 0x7FFFu + ((u >> 16) & 1u);
    return (unsigned short)(r >> 16);
}
static __device__ __forceinline__ float bf2f(unsigned short u) {
    unsigned v = ((unsigned)u) << 16;
    return __builtin_bit_cast(float, v);
}
static __device__ __forceinline__ float sigf(float x) { return 1.0f / (1.0f + __expf(-x)); }
static __device__ __forceinline__ float tanh_(float x) { return 1.0f - 2.0f / (__expf(2.0f * x) + 1.0f); }

__global__ void k_init_sched(int* cnt, int* cur, int* maxd) {
    int g = blockIdx.x * 256 + threadIdx.x;
    if (g < NN + 2) { cnt[g] = 0; cur[g] = 0; }
    if (g == 0) maxd[0] = 0;
}

// Poison C (f32 NaN) and Hb (bf16 -NaN pairs). Grid 2048 x 256.
__global__ void k_poison(float* C, unsigned* HbU) {
    const int g = blockIdx.x * 256 + threadIdx.x;
    const uint4_ sc = (uint4_){SENT_C, SENT_C, SENT_C, SENT_C};
    const uint4_ sh = (uint4_){SENT_H, SENT_H, SENT_H, SENT_H};
    uint4_* Cu = (uint4_*)C;
    uint4_* Hu = (uint4_*)HbU;
    #pragma unroll
    for (int k = 0; k < 4; ++k) Cu[(size_t)g + (size_t)k * 524288] = sc;
    #pragma unroll
    for (int k = 0; k < 2; ++k) Hu[(size_t)g + (size_t)k * 524288] = sh;
}

__global__ void k_root(const float* __restrict__ X, const float* __restrict__ state,
                       const float* __restrict__ rootW, const float* __restrict__ rootb,
                       const int* __restrict__ idx,
                       unsigned short* __restrict__ Hb, float* __restrict__ C) {
    const int t = threadIdx.x;
    const int row = idx[0];
    const float4_* xr = (const float4_*)(X + (size_t)row * DD);
    const float4_* wr = (const float4_*)(rootW + (size_t)t * DD);
    float acc = rootb[t];
    for (int k = 0; k < DD / 4; ++k) {
        float4_ a = xr[k], b = wr[k];
        acc += a[0] * b[0] + a[1] * b[1] + a[2] * b[2] + a[3] * b[3];
    }
    Hb[t] = f2bf(tanh_(acc));
    C[t] = state[t];
}

__global__ void k_dep_init(const int* __restrict__ parents, int* dep, int* jmp) {
    int i = blockIdx.x * 256 + threadIdx.x;
    if (i >= NN) return;
    dep[i] = (i == 0) ? 0 : 1;
    jmp[i] = (i == 0) ? 0 : parents[i];
}

__global__ void k_dep_step(const int* __restrict__ depA, const int* __restrict__ jmpA,
                           int* __restrict__ depB, int* __restrict__ jmpB) {
    int i = blockIdx.x * 256 + threadIdx.x;
    if (i >= NN) return;
    int j = jmpA[i];
    depB[i] = depA[i] + depA[j];
    jmpB[i] = jmpA[j];
}

__global__ void k_hist(const int* __restrict__ dep, int* cnt, int* maxd) {
    int i = blockIdx.x * 256 + threadIdx.x;
    if (i >= NN) return;
    int d = dep[i];
    atomicAdd(&cnt[d], 1);
    atomicMax(&maxd[0], d);
}

__global__ void k_scan(const int* __restrict__ cnt, int* __restrict__ off) {
    __shared__ int sums[256];
    const int tid = threadIdx.x;
    const int base = tid * 128;
    int s = 0;
    for (int k = 0; k < 128; ++k) s += cnt[base + k];
    sums[tid] = s;
    __syncthreads();
    if (tid == 0) {
        int run = 0;
        for (int t = 0; t < 256; ++t) { int tmp = sums[t]; sums[t] = run; run += tmp; }
    }
    __syncthreads();
    int run = sums[tid];
    for (int k = 0; k < 128; ++k) { off[base + k] = run; run += cnt[base + k]; }
    if (tid == 255) off[NN] = run;
}

__global__ void k_scatter(const int* __restrict__ dep, const int* __restrict__ off,
                          int* cur, int* __restrict__ lev) {
    int i = blockIdx.x * 256 + threadIdx.x;
    if (i >= NN) return;
    int d = dep[i];
    int pos = off[d] + atomicAdd(&cur[d], 1);
    lev[pos] = i;
}

// Throughput GEMM: Gpre[n][g] = X[idx[n]]·Wih[g] + bih[g] + bhh[g], bf16 out.
__global__ __launch_bounds__(256, 1) void k_gx(
    const float* __restrict__ X, const float* __restrict__ Wih,
    const float* __restrict__ bih, const float* __restrict__ bhh,
    const int* __restrict__ idx, unsigned short* __restrict__ Gp) {
    __shared__ __align__(16) short bw_s[128 * 264];
    __shared__ float bias_s[128];
    const int tid = threadIdx.x;
    const int w = tid >> 6, l = tid & 63;
    const int lanelo = l & 15, quad = l >> 4;

    short8 a[2][8];
    #pragma unroll
    for (int ti = 0; ti < 2; ++ti) {
        int n = (blockIdx.x * 8 + w * 2 + ti) * 16 + lanelo;
        int row = idx[n];
        const float* xp = X + (size_t)row * DD + quad * 8;
        #pragma unroll
        for (int ks = 0; ks < 8; ++ks) {
            float4_ x0 = *(const float4_*)(xp + ks * 32);
            float4_ x1 = *(const float4_*)(xp + ks * 32 + 4);
            short8 s;
            s[0] = f2bf(x0[0]); s[1] = f2bf(x0[1]); s[2] = f2bf(x0[2]); s[3] = f2bf(x0[3]);
            s[4] = f2bf(x1[0]); s[5] = f2bf(x1[1]); s[6] = f2bf(x1[2]); s[7] = f2bf(x1[3]);
            a[ti][ks] = s;
        }
    }
    for (int gc = 0; gc < 8; ++gc) {
        __syncthreads();
        for (int e = tid; e < 128 * 64; e += 256) {
            int r = e >> 6, c4 = (e & 63) * 4;
            float4_ b = *(const float4_*)(Wih + (size_t)(gc * 128 + r) * DD + c4);
            unsigned short* pb = (unsigned short*)&bw_s[r * 264 + c4];
            pb[0] = f2bf(b[0]); pb[1] = f2bf(b[1]); pb[2] = f2bf(b[2]); pb[3] = f2bf(b[3]);
        }
        if (tid < 128) bias_s[tid] = bih[gc * 128 + tid] + bhh[gc * 128 + tid];
        __syncthreads();
        #pragma unroll
        for (int ntl = 0; ntl < 8; ++ntl) {
            float4_ acc0 = (float4_){0.f, 0.f, 0.f, 0.f};
            float4_ acc1 = (float4_){0.f, 0.f, 0.f, 0.f};
            #pragma unroll
            for (int ks = 0; ks < 8; ++ks) {
                short8 bf = *(const short8*)&bw_s[(ntl * 16 + lanelo) * 264 + ks * 32 + quad * 8];
                acc0 = __builtin_amdgcn_mfma_f32_16x16x32_bf16(a[0][ks], bf, acc0, 0, 0, 0);
                acc1 = __builtin_amdgcn_mfma_f32_16x16x32_bf16(a[1][ks], bf, acc1, 0, 0, 0);
            }
            float bia = bias_s[ntl * 16 + lanelo];
            int g = gc * 128 + ntl * 16 + lanelo;
            int nb0 = (blockIdx.x * 8 + w * 2) * 16 + quad * 4;
            #pragma unroll
            for (int r = 0; r < 4; ++r) {
                Gp[(size_t)(nb0 + r) * GP + g] = f2bf(acc0[r] + bia);
                Gp[(size_t)(nb0 + 16 + r) * GP + g] = f2bf(acc1[r] + bia);
            }
        }
    }
}

// 256 blocks x 256 threads = 1024 independent wave engines.
// Block j = blockIdx&7 owns hcols [j*32, +32); wave w owns [j*32+w*8, +8)
// x all 4 gates (2 MFMA tiles: ti0 = i|f rows, ti1 = g|o rows).
// Zero LDS, zero barriers in the loop; one vmcnt drain per tile (producer).
__global__ __launch_bounds__(256, 1) void k_tree2(
    const float* __restrict__ Whh,
    const int* __restrict__ parents,
    const int* __restrict__ off, const int* __restrict__ lev, const int* __restrict__ maxd_g,
    const unsigned short* __restrict__ Gp,
    unsigned short* __restrict__ Hb, float* __restrict__ C) {

    const int tid = threadIdx.x;
    const int w = tid >> 6;              // wave 0..3
    const int l = tid & 63;
    const int lanelo = l & 15, quad = l >> 4;
    const int j = blockIdx.x & 7, grp = blockIdx.x >> 3;
    const int colbase = j * 32 + w * 8;  // wave's 8 hcols
    const bool ew = (lanelo < 8);        // elementwise-owner lanes
    const int col = colbase + lanelo;    // valid for ew lanes

    // W_hh B-fragments in registers (64 VGPRs): wf[ti][ks].
    // B-col n=lanelo: gate = ti*2 + (lanelo>>3), hcol = colbase + (lanelo&7).
    short8 wf[2][8];
    #pragma unroll
    for (int ti = 0; ti < 2; ++ti) {
        const int G = (ti * 2 + (lanelo >> 3)) * 256 + colbase + (lanelo & 7);
        const float* wr = Whh + (size_t)G * DD;
        #pragma unroll
        for (int ks = 0; ks < 8; ++ks) {
            float4_ lo4 = *(const float4_*)(wr + ks * 32 + quad * 8);
            float4_ hi4 = *(const float4_*)(wr + ks * 32 + quad * 8 + 4);
            short8 s;
            s[0] = f2bf(lo4[0]); s[1] = f2bf(lo4[1]); s[2] = f2bf(lo4[2]); s[3] = f2bf(lo4[3]);
            s[4] = f2bf(hi4[0]); s[5] = f2bf(hi4[1]); s[6] = f2bf(hi4[2]); s[7] = f2bf(hi4[3]);
            wf[ti][ks] = s;
        }
    }

    const unsigned* HbU = (const unsigned*)Hb;
    unsigned* HbW = (unsigned*)Hb;
    const unsigned* Cw = (const unsigned*)C;
    const int maxd = maxd_g[0];
    const int G0 = (lanelo >> 3) * 256 + colbase + (lanelo & 7);   // Gpre rows
    const int G1 = G0 + 512;

    int pnA = -1, ppA = 0;
    bool pn_valid = false;

    int lo = off[1];
    for (int d = 1; d <= maxd; ++d) {
        const int hi = off[d + 1];
        const int tiles = (hi - lo + 15) >> 4;
        for (int t = grp; t < tiles; t += 32) {
            const int base = lo + t * 16;
            // Tile ids: A-row for this lane = node (base+lanelo).
            int nodeA, parA;
            if (pn_valid) { nodeA = pnA; parA = ppA; }
            else {
                nodeA = -1; parA = 0;
                if (base + lanelo < hi) { nodeA = lev[base + lanelo]; parA = parents[nodeA]; }
            }
            pn_valid = false;
            // Volley: parent-H A-fragment (32 dwords/lane, MFMA layout).
            unsigned aw[32];
            const unsigned* hb = HbU + (size_t)parA * 128 + quad * 4;
            #pragma unroll
            for (int k = 0; k < 32; ++k)
                aw[k] = (nodeA >= 0) ? ATL(&hb[(k >> 2) * 16 + (k & 3)]) : 0u;
            // Output-row ids via shuffle (lanes 0..15 hold rows 0..15).
            int nd2[4], pr2[4];
            #pragma unroll
            for (int r = 0; r < 4; ++r) {
                nd2[r] = __shfl(nodeA, quad * 4 + r);
                pr2[r] = __shfl(parA, quad * 4 + r);
            }
            // Parent C (ew lanes only).
            unsigned cwv[4];
            #pragma unroll
            for (int r = 0; r < 4; ++r)
                cwv[r] = (ew && nd2[r] >= 0) ? ATL(&Cw[(size_t)pr2[r] * DD + col]) : 0u;
            // Gpre (static, cached).
            unsigned short gp0[4], gp1[4];
            #pragma unroll
            for (int r = 0; r < 4; ++r) {
                gp0[r] = (nd2[r] >= 0) ? Gp[(size_t)nd2[r] * GP + G0] : (unsigned short)0;
                gp1[r] = (nd2[r] >= 0) ? Gp[(size_t)nd2[r] * GP + G1] : (unsigned short)0;
            }
            // Next-tile id prefetch (hides the lev->parents chain under the spin).
            {
                int nt_base = -1, nt_hi = hi;
                if (t + 32 < tiles) {
                    nt_base = lo + (t + 32) * 16;
                } else if (d < maxd) {
                    const int hi2 = off[d + 2];
                    const int tiles2 = (hi2 - hi + 15) >> 4;
                    if (grp < tiles2) { nt_base = hi + grp * 16; nt_hi = hi2; }
                }
                if (nt_base >= 0) {
                    pnA = -1; ppA = 0;
                    if (nt_base + lanelo < nt_hi) { pnA = lev[nt_base + lanelo]; ppA = parents[pnA]; }
                    pn_valid = true;
                }
            }
            // Sentinel waits: RT-paced spin on aw[0], then per-word revalidate.
            if (nodeA >= 0) {
                while (aw[0] == SENT_H) {
                    __builtin_amdgcn_s_sleep(1);
                    aw[0] = ATL(&hb[0]);
                }
                #pragma unroll
                for (int k = 1; k < 32; ++k)
                    while (aw[k] == SENT_H) {
                        __builtin_amdgcn_s_sleep(1);
                        aw[k] = ATL(&hb[(k >> 2) * 16 + (k & 3)]);
                    }
            }
            #pragma unroll
            for (int r = 0; r < 4; ++r)
                if (ew && nd2[r] >= 0)
                    while (cwv[r] == SENT_C) {
                        __builtin_amdgcn_s_sleep(1);
                        cwv[r] = ATL(&Cw[(size_t)pr2[r] * DD + col]);
                    }
            // MFMA: 2 tiles x 8 K-slices, all operands in VGPRs.
            float4_ acc0 = (float4_){0.f, 0.f, 0.f, 0.f};
            float4_ acc1 = (float4_){0.f, 0.f, 0.f, 0.f};
            #pragma unroll
            for (int ks = 0; ks < 8; ++ks) {
                uint4_ u = (uint4_){aw[ks * 4], aw[ks * 4 + 1], aw[ks * 4 + 2], aw[ks * 4 + 3]};
                short8 af = __builtin_bit_cast(short8, u);
                acc0 = __builtin_amdgcn_mfma_f32_16x16x32_bf16(af, wf[0][ks], acc0, 0, 0, 0);
                acc1 = __builtin_amdgcn_mfma_f32_16x16x32_bf16(af, wf[1][ks], acc1, 0, 0, 0);
            }
            // Gpre add; f/o live 8 lanes over -> one shfl_xor(8); elementwise
            // on ew lanes; relaxed stores + one vmcnt drain (visibility).
            #pragma unroll
            for (int r = 0; r < 4; ++r) {
                float a0 = acc0[r] + bf2f(gp0[r]);   // lanes<8: i, lanes>=8: f
                float a1 = acc1[r] + bf2f(gp1[r]);   // lanes<8: g, lanes>=8: o
                float fg = __shfl_xor(a0, 8);
                float og = __shfl_xor(a1, 8);
                float cp = __builtin_bit_cast(float, cwv[r]);
                float cn = sigf(fg) * cp + sigf(a0) * tanh_(a1);
                float hn = sigf(og) * tanh_(cn);
                unsigned short hs = f2bf(hn);
                unsigned pair = ((unsigned)hs) |
                                (((unsigned)(unsigned short)__shfl_down((int)hs, 1)) << 16);
                if (ew && nd2[r] >= 0) {
                    ATS(&C[(size_t)nd2[r] * DD + col], cn);
                    if ((lanelo & 1) == 0)
                        ATS(&HbW[(size_t)nd2[r] * 128 + (col >> 1)], pair);
                }
            }
            // Producer drain: force stores to the coherence point before the
            // engine moves on (r5-r9 proven; removing it = r11 container death).
            asm volatile("s_waitcnt vmcnt(0)" ::: "memory");
        }
        lo = hi;
    }
}

__global__ void k_out(const unsigned short* __restrict__ Hb, const float* __restrict__ C,
                      const int* __restrict__ idx, float* __restrict__ out) {
    const int b = blockIdx.x, t = threadIdx.x;
    if (b < NN) {
        int drow = idx[b];
        out[512 + (size_t)drow * DD + t] = bf2f(Hb[(size_t)b * DD + t]);
    } else {
        out[t] = C[t];
        out[DD + t] = bf2f(Hb[t]);
    }
}

extern "C" void kernel_launch(void* const* d_in, const int* in_sizes, int n_in,
                              void* d_out, int out_size, void* d_ws, size_t ws_size,
                              hipStream_t stream) {
    const float* X     = (const float*)d_in[0];
    const float* state = (const float*)d_in[1];
    const float* rootW = (const float*)d_in[2];
    const float* rootb = (const float*)d_in[3];
    const float* Wih   = (const float*)d_in[4];
    const float* Whh   = (const float*)d_in[5];
    const float* bih   = (const float*)d_in[6];
    const float* bhh   = (const float*)d_in[7];
    const int* parents = (const int*)d_in[8];
    const int* idx     = (const int*)d_in[9];

    float* C           = (float*)d_ws;                                   // 32 MiB
    unsigned short* Hb = (unsigned short*)(C + (size_t)NN * DD);         // 16 MiB
    unsigned short* Gp = Hb + (size_t)NN * DD;                           // 64 MiB
    int* ip            = (int*)(Gp + (size_t)NN * GP);
    int* depA = ip;            ip += NN;
    int* jmpA = ip;            ip += NN;
    int* depB = ip;            ip += NN;
    int* jmpB = ip;            ip += NN;
    int* cnt  = ip;            ip += NN + 2;
    int* off  = ip;            ip += NN + 2;
    int* cur  = ip;            ip += NN + 2;
    int* lev  = ip;            ip += NN;
    int* maxd = ip;            ip += 8;
    float* out = (float*)d_out;

    k_init_sched<<<dim3(129), dim3(256), 0, stream>>>(cnt, cur, maxd);
    k_dep_init<<<dim3(128), dim3(256), 0, stream>>>(parents, depA, jmpA);
    int* dA = depA; int* jA = jmpA; int* dB = depB; int* jB = jmpB;
    for (int it = 0; it < 15; ++it) {
        k_dep_step<<<dim3(128), dim3(256), 0, stream>>>(dA, jA, dB, jB);
        int* tp;
        tp = dA; dA = dB; dB = tp;
        tp = jA; jA = jB; jB = tp;
    }
    k_hist<<<dim3(128), dim3(256), 0, stream>>>(dA, cnt, maxd);
    k_scan<<<dim3(1), dim3(256), 0, stream>>>(cnt, off);
    k_scatter<<<dim3(128), dim3(256), 0, stream>>>(dA, off, cur, lev);

    k_gx<<<dim3(256), dim3(256), 0, stream>>>(X, Wih, bih, bhh, idx, Gp);

    k_poison<<<dim3(2048), dim3(256), 0, stream>>>(C, (unsigned*)Hb);
    k_root<<<dim3(1), dim3(256), 0, stream>>>(X, state, rootW, rootb, idx, Hb, C);
    k_tree2<<<dim3(256), dim3(256), 0, stream>>>(Whh, parents, off, lev, maxd, Gp, Hb, C);
    k_out<<<dim3(NN + 1), dim3(256), 0, stream>>>(Hb, C, idx, out);
}

// Round 8
// 2766.557 us; speedup vs baseline: 4.2307x; 1.9772x over previous
//
#include <hip/hip_runtime.h>

// TopDownTreeLSTM on MI355X — round 13: r8 skeleton, machinery surgery.
// Measured (r10): maxd~1370, r8 hop 1.07us = 0.50 machinery + 0.57 wait
// (~2 LLC RT, structural for the 8-way column split). r9/r12 showed
// "W in VGPR + scalar retry loads" triggers compiler spills (VGPR=80/144,
// FETCH +110MB). r13 keeps W in LDS and r8's coalesced A_s staging, but:
//  - W re-laid per-wave (wave owns 8 hcols x 4 gates) -> gates land in-lane,
//    f/o via one shfl_xor(8) (r12-verified math) -> R_s DELETED.
//  - node ids via redundant cached loads + __shfl -> nd_s/par_s DELETED.
//  - Gpre via per-lane scalar loads (static, L2-hot) -> G_s DELETED.
//  - poll: volley-first; miss -> per-WAVE 8-lane tight sentry + per-word
//    revalidate -> no block-vote barrier.
// Per tile: 2 barriers, 1 LDS round trip (A_s), 1 drain (fence wg-release).

#define NN 32768
#define DD 256
#define GP 1024
#define OFFCAP 4096
#define SENT_C 0x7FC00001u   // f32 NaN payload: real c is always finite
#define SENT_H 0xFFFFFFFFu   // bf16 -NaN pair: real h in (-1,1)

typedef __attribute__((ext_vector_type(8))) short short8;
typedef __attribute__((ext_vector_type(4))) float float4_;
typedef __attribute__((ext_vector_type(4))) unsigned uint4_;

#define ATL(p) __hip_atomic_load((p), __ATOMIC_RELAXED, __HIP_MEMORY_SCOPE_AGENT)
#define ATS(p, v) __hip_atomic_store((p), (v), __ATOMIC_RELAXED, __HIP_MEMORY_SCOPE_AGENT)

static __device__ __forceinline__ unsigned short f2bf(float f) {
    unsigned u = __builtin_bit_cast(unsigned, f);
    unsigned r = u + 0x7FFFu + ((u >> 16) & 1u);
    return (unsigned short)(r >> 16);
}
static __device__ __forceinline__ float bf2f(unsigned short u) {
    unsigned v = ((unsigned)u) << 16;
    return __builtin_bit_cast(float, v);
}
static __device__ __forceinline__ float sigf(float x) { return 1.0f / (1.0f + __expf(-x)); }
static __device__ __forceinline__ float tanh_(float x) { return 1.0f - 2.0f / (__expf(2.0f * x) + 1.0f); }

__global__ void k_init_sched(int* cnt, int* cur, int* maxd) {
    int g = blockIdx.x * 256 + threadIdx.x;
    if (g < NN + 2) { cnt[g] = 0; cur[g] = 0; }
    if (g == 0) maxd[0] = 0;
}

// Poison C (f32 NaN) and Hb (bf16 -NaN pairs). Grid 2048 x 256.
__global__ void k_poison(float* C, unsigned* HbU) {
    const int g = blockIdx.x * 256 + threadIdx.x;
    const uint4_ sc = (uint4_){SENT_C, SENT_C, SENT_C, SENT_C};
    const uint4_ sh = (uint4_){SENT_H, SENT_H, SENT_H, SENT_H};
    uint4_* Cu = (uint4_*)C;
    uint4_* Hu = (uint4_*)HbU;
    #pragma unroll
    for (int k = 0; k < 4; ++k) Cu[(size_t)g + (size_t)k * 524288] = sc;
    #pragma unroll
    for (int k = 0; k < 2; ++k) Hu[(size_t)g + (size_t)k * 524288] = sh;
}

__global__ void k_root(const float* __restrict__ X, const float* __restrict__ state,
                       const float* __restrict__ rootW, const float* __restrict__ rootb,
                       const int* __restrict__ idx,
                       unsigned short* __restrict__ Hb, float* __restrict__ C) {
    const int t = threadIdx.x;
    const int row = idx[0];
    const float4_* xr = (const float4_*)(X + (size_t)row * DD);
    const float4_* wr = (const float4_*)(rootW + (size_t)t * DD);
    float acc = rootb[t];
    for (int k = 0; k < DD / 4; ++k) {
        float4_ a = xr[k], b = wr[k];
        acc += a[0] * b[0] + a[1] * b[1] + a[2] * b[2] + a[3] * b[3];
    }
    Hb[t] = f2bf(tanh_(acc));
    C[t] = state[t];
}

__global__ void k_dep_init(const int* __restrict__ parents, int* dep, int* jmp) {
    int i = blockIdx.x * 256 + threadIdx.x;
    if (i >= NN) return;
    dep[i] = (i == 0) ? 0 : 1;
    jmp[i] = (i == 0) ? 0 : parents[i];
}

__global__ void k_dep_step(const int* __restrict__ depA, const int* __restrict__ jmpA,
                           int* __restrict__ depB, int* __restrict__ jmpB) {
    int i = blockIdx.x * 256 + threadIdx.x;
    if (i >= NN) return;
    int j = jmpA[i];
    depB[i] = depA[i] + depA[j];
    jmpB[i] = jmpA[j];
}

__global__ void k_hist(const int* __restrict__ dep, int* cnt, int* maxd) {
    int i = blockIdx.x * 256 + threadIdx.x;
    if (i >= NN) return;
    int d = dep[i];
    atomicAdd(&cnt[d], 1);
    atomicMax(&maxd[0], d);
}

__global__ void k_scan(const int* __restrict__ cnt, int* __restrict__ off) {
    __shared__ int sums[256];
    const int tid = threadIdx.x;
    const int base = tid * 128;
    int s = 0;
    for (int k = 0; k < 128; ++k) s += cnt[base + k];
    sums[tid] = s;
    __syncthreads();
    if (tid == 0) {
        int run = 0;
        for (int t = 0; t < 256; ++t) { int tmp = sums[t]; sums[t] = run; run += tmp; }
    }
    __syncthreads();
    int run = sums[tid];
    for (int k = 0; k < 128; ++k) { off[base + k] = run; run += cnt[base + k]; }
    if (tid == 255) off[NN] = run;
}

__global__ void k_scatter(const int* __restrict__ dep, const int* __restrict__ off,
                          int* cur, int* __restrict__ lev) {
    int i = blockIdx.x * 256 + threadIdx.x;
    if (i >= NN) return;
    int d = dep[i];
    int pos = off[d] + atomicAdd(&cur[d], 1);
    lev[pos] = i;
}

// Throughput GEMM: Gpre[n][g] = X[idx[n]]·Wih[g] + bih[g] + bhh[g], bf16 out.
__global__ __launch_bounds__(256, 1) void k_gx(
    const float* __restrict__ X, const float* __restrict__ Wih,
    const float* __restrict__ bih, const float* __restrict__ bhh,
    const int* __restrict__ idx, unsigned short* __restrict__ Gp) {
    __shared__ __align__(16) short bw_s[128 * 264];
    __shared__ float bias_s[128];
    const int tid = threadIdx.x;
    const int w = tid >> 6, l = tid & 63;
    const int lanelo = l & 15, quad = l >> 4;

    short8 a[2][8];
    #pragma unroll
    for (int ti = 0; ti < 2; ++ti) {
        int n = (blockIdx.x * 8 + w * 2 + ti) * 16 + lanelo;
        int row = idx[n];
        const float* xp = X + (size_t)row * DD + quad * 8;
        #pragma unroll
        for (int ks = 0; ks < 8; ++ks) {
            float4_ x0 = *(const float4_*)(xp + ks * 32);
            float4_ x1 = *(const float4_*)(xp + ks * 32 + 4);
            short8 s;
            s[0] = f2bf(x0[0]); s[1] = f2bf(x0[1]); s[2] = f2bf(x0[2]); s[3] = f2bf(x0[3]);
            s[4] = f2bf(x1[0]); s[5] = f2bf(x1[1]); s[6] = f2bf(x1[2]); s[7] = f2bf(x1[3]);
            a[ti][ks] = s;
        }
    }
    for (int gc = 0; gc < 8; ++gc) {
        __syncthreads();
        for (int e = tid; e < 128 * 64; e += 256) {
            int r = e >> 6, c4 = (e & 63) * 4;
            float4_ b = *(const float4_*)(Wih + (size_t)(gc * 128 + r) * DD + c4);
            unsigned short* pb = (unsigned short*)&bw_s[r * 264 + c4];
            pb[0] = f2bf(b[0]); pb[1] = f2bf(b[1]); pb[2] = f2bf(b[2]); pb[3] = f2bf(b[3]);
        }
        if (tid < 128) bias_s[tid] = bih[gc * 128 + tid] + bhh[gc * 128 + tid];
        __syncthreads();
        #pragma unroll
        for (int ntl = 0; ntl < 8; ++ntl) {
            float4_ acc0 = (float4_){0.f, 0.f, 0.f, 0.f};
            float4_ acc1 = (float4_){0.f, 0.f, 0.f, 0.f};
            #pragma unroll
            for (int ks = 0; ks < 8; ++ks) {
                short8 bf = *(const short8*)&bw_s[(ntl * 16 + lanelo) * 264 + ks * 32 + quad * 8];
                acc0 = __builtin_amdgcn_mfma_f32_16x16x32_bf16(a[0][ks], bf, acc0, 0, 0, 0);
                acc1 = __builtin_amdgcn_mfma_f32_16x16x32_bf16(a[1][ks], bf, acc1, 0, 0, 0);
            }
            float bia = bias_s[ntl * 16 + lanelo];
            int g = gc * 128 + ntl * 16 + lanelo;
            int nb0 = (blockIdx.x * 8 + w * 2) * 16 + quad * 4;
            #pragma unroll
            for (int r = 0; r < 4; ++r) {
                Gp[(size_t)(nb0 + r) * GP + g] = f2bf(acc0[r] + bia);
                Gp[(size_t)(nb0 + 16 + r) * GP + g] = f2bf(acc1[r] + bia);
            }
        }
    }
}

// 256 blocks (32 groups x 8 j) x 256 threads. Wave w owns hcols
// [j*32 + w*8, +8) x all 4 gates (2 B-tiles). W in LDS (per-wave layout),
// A_s staged from coalesced agent dword loads (the loads ARE the poll).
__global__ __launch_bounds__(256, 1) void k_tree2(
    const float* __restrict__ Whh,
    const int* __restrict__ parents,
    const int* __restrict__ off, const int* __restrict__ lev, const int* __restrict__ maxd_g,
    const unsigned short* __restrict__ Gp,
    unsigned short* __restrict__ Hb, float* __restrict__ C) {

    __shared__ __align__(16) short w_s[128 * 264];   // W_hh slice, per-wave tiles
    __shared__ __align__(16) short A_s[16 * 264];    // parent H rows, bf16
    __shared__ int off_s[OFFCAP];                    // level offsets (LDS-rate)

    const int tid = threadIdx.x;
    const int w = tid >> 6, l = tid & 63;
    const int lanelo = l & 15, quad = l >> 4;
    const int j = blockIdx.x & 7, grp = blockIdx.x >> 3;
    const int mhalf = tid >> 7;            // staging row parity (0: even rows, 1: odd)
    const int cu = tid & 127;              // staging dword col
    const int colbase = j * 32 + w * 8;    // wave's 8 hcols
    const bool ewl = (lanelo < 8);         // elementwise-owner lanes
    const int col = colbase + (lanelo & 7);

    // Stage W_hh, per-wave layout: local r = w'*32 + ti*16 + n ->
    // gate-row G = (ti*2 + (n>>3))*256 + j*32 + w'*8 + (n&7).
    for (int e = tid; e < 128 * 64; e += 256) {
        int r = e >> 6, c4 = (e & 63) * 4;
        int wp = r >> 5, ti = (r >> 4) & 1, n = r & 15;
        int G = (ti * 2 + (n >> 3)) * 256 + j * 32 + wp * 8 + (n & 7);
        float4_ b = *(const float4_*)(Whh + (size_t)G * DD + c4);
        unsigned short* pb = (unsigned short*)&w_s[r * 264 + c4];
        pb[0] = f2bf(b[0]); pb[1] = f2bf(b[1]); pb[2] = f2bf(b[2]); pb[3] = f2bf(b[3]);
    }
    const int maxd = maxd_g[0];
    const int staged = (maxd + 2 < OFFCAP) ? (maxd + 2) : OFFCAP;
    for (int e = tid; e < staged; e += 256) off_s[e] = off[e];
    __syncthreads();

    #define OFFS(i) (((i) < staged) ? off_s[(i)] : off[(i)])

    const unsigned* HbU = (const unsigned*)Hb;
    unsigned* HbW = (unsigned*)Hb;
    const unsigned* Cw = (const unsigned*)C;
    const int G0 = (lanelo >> 3) * 256 + colbase + (lanelo & 7);   // i|f Gpre row
    const int G1 = G0 + 512;                                       // g|o Gpre row

    int pnA = -1, ppA = 0;
    bool pn_valid = false;

    int lo = OFFS(1);
    for (int d = 1; d <= maxd; ++d) {
        const int hi = OFFS(d + 1);
        const int tiles = (hi - lo + 15) >> 4;
        for (int t = grp; t < tiles; t += 32) {
            const int base = lo + t * 16;
            // Node ids: every lane loads its lanelo-row id (cached, redundant
            // across waves); wave-internal __shfl distributes them.
            int nodeA, parA;
            if (pn_valid) { nodeA = pnA; parA = ppA; }
            else {
                nodeA = -1; parA = 0;
                int ii = base + lanelo;
                if (ii < hi) { nodeA = lev[ii]; parA = parents[nodeA]; }
            }
            pn_valid = false;
            // Volley: 8 coherent dwords/thread of parent H (rows mhalf+2k).
            unsigned hv[8]; int pm[8];
            #pragma unroll
            for (int k2 = 0; k2 < 8; ++k2) {
                int m = mhalf + 2 * k2;
                int nd = __shfl(nodeA, m);
                int pp = __shfl(parA, m);
                pm[k2] = (nd >= 0) ? pp : -1;
                hv[k2] = (pm[k2] >= 0) ? ATL(&HbU[(size_t)pm[k2] * 128 + cu]) : 0u;
            }
            // Output-row ids + parent C + Gpre (static) for the elementwise.
            int nd2[4], pr2[4];
            #pragma unroll
            for (int r = 0; r < 4; ++r) {
                nd2[r] = __shfl(nodeA, quad * 4 + r);
                pr2[r] = __shfl(parA, quad * 4 + r);
            }
            unsigned cwv[4];
            #pragma unroll
            for (int r = 0; r < 4; ++r)
                cwv[r] = (ewl && nd2[r] >= 0) ? ATL(&Cw[(size_t)pr2[r] * DD + col]) : 0u;
            unsigned short gp0[4], gp1[4];
            #pragma unroll
            for (int r = 0; r < 4; ++r) {
                gp0[r] = (nd2[r] >= 0) ? Gp[(size_t)nd2[r] * GP + G0] : (unsigned short)0;
                gp1[r] = (nd2[r] >= 0) ? Gp[(size_t)nd2[r] * GP + G1] : (unsigned short)0;
            }
            // Next-tile id prefetch (dependent chain hides under the poll).
            {
                int nt_base = -1, nt_hi = hi;
                if (t + 32 < tiles) {
                    nt_base = lo + (t + 32) * 16;
                } else if (d < maxd) {
                    const int hi2 = OFFS(d + 2);
                    const int tiles2 = (hi2 - hi + 15) >> 4;
                    if (grp < tiles2) { nt_base = hi + grp * 16; nt_hi = hi2; }
                }
                if (nt_base >= 0) {
                    pnA = -1; ppA = 0;
                    int ii = nt_base + lanelo;
                    if (ii < nt_hi) { pnA = lev[ii]; ppA = parents[pnA]; }
                    pn_valid = true;
                }
            }
            // Wave-level gate: if any word missed, cheap 8-lane tight sentry
            // (idle blocks live here), then per-word revalidation.
            bool allok = true;
            #pragma unroll
            for (int k2 = 0; k2 < 8; ++k2)
                if (pm[k2] >= 0 && hv[k2] == SENT_H) allok = false;
            #pragma unroll
            for (int r = 0; r < 4; ++r)
                if (ewl && nd2[r] >= 0 && cwv[r] == SENT_C) allok = false;
            if (__any(allok ? 0 : 1)) {
                int sm = mhalf + 2 * (l & 7);
                int snd = __shfl(nodeA, sm);
                int spar = __shfl(parA, sm);
                const bool act = (l < 8) && (snd >= 0);
                const unsigned* sp = &HbU[(size_t)spar * 128];
                bool miss = act && (ATL(sp) == SENT_H);
                while (__any(miss ? 1 : 0))
                    miss = act && (ATL(sp) == SENT_H);
                #pragma unroll
                for (int k2 = 0; k2 < 8; ++k2)
                    if (pm[k2] >= 0)
                        while (hv[k2] == SENT_H) {
                            __builtin_amdgcn_s_sleep(1);
                            hv[k2] = ATL(&HbU[(size_t)pm[k2] * 128 + cu]);
                        }
                #pragma unroll
                for (int r = 0; r < 4; ++r)
                    if (ewl && nd2[r] >= 0)
                        while (cwv[r] == SENT_C) {
                            __builtin_amdgcn_s_sleep(1);
                            cwv[r] = ATL(&Cw[(size_t)pr2[r] * DD + col]);
                        }
            }
            // Stage parent H into A_s; barrier #1.
            #pragma unroll
            for (int k2 = 0; k2 < 8; ++k2)
                *(unsigned*)&A_s[(mhalf + 2 * k2) * 264 + cu * 2] = hv[k2];
            __syncthreads();
            // MFMA: A from A_s, B from w_s per-wave tiles; gates land in-lane.
            float4_ acc0 = (float4_){0.f, 0.f, 0.f, 0.f};
            float4_ acc1 = (float4_){0.f, 0.f, 0.f, 0.f};
            {
                short8 af[8];
                #pragma unroll
                for (int ks = 0; ks < 8; ++ks)
                    af[ks] = *(const short8*)&A_s[lanelo * 264 + ks * 32 + quad * 8];
                #pragma unroll
                for (int ks = 0; ks < 8; ++ks) {
                    short8 b0 = *(const short8*)&w_s[(w * 32 + lanelo) * 264 + ks * 32 + quad * 8];
                    short8 b1 = *(const short8*)&w_s[(w * 32 + 16 + lanelo) * 264 + ks * 32 + quad * 8];
                    acc0 = __builtin_amdgcn_mfma_f32_16x16x32_bf16(af[ks], b0, acc0, 0, 0, 0);
                    acc1 = __builtin_amdgcn_mfma_f32_16x16x32_bf16(af[ks], b1, acc1, 0, 0, 0);
                }
            }
            // Elementwise in registers (r12-verified): lanes<8 hold i|g,
            // lanes 8-15 hold f|o for the same hcols -> one shfl_xor(8).
            #pragma unroll
            for (int r = 0; r < 4; ++r) {
                float a0 = acc0[r] + bf2f(gp0[r]);   // i (lanes<8) | f (lanes>=8)
                float a1 = acc1[r] + bf2f(gp1[r]);   // g (lanes<8) | o (lanes>=8)
                float fg = __shfl_xor(a0, 8);
                float og = __shfl_xor(a1, 8);
                float cp = __builtin_bit_cast(float, cwv[r]);
                float cn = sigf(fg) * cp + sigf(a0) * tanh_(a1);
                float hn = sigf(og) * tanh_(cn);
                unsigned short hs = f2bf(hn);
                unsigned pair = ((unsigned)hs) |
                                (((unsigned)(unsigned short)__shfl_down((int)hs, 1)) << 16);
                if (ewl && nd2[r] >= 0) {
                    ATS(&C[(size_t)nd2[r] * DD + col], cn);
                    if ((lanelo & 1) == 0)
                        ATS(&HbW[(size_t)nd2[r] * 128 + (col >> 1)], pair);
                }
            }
            // Drain stores to the coherence point; barrier #2 protects A_s.
            __builtin_amdgcn_fence(__ATOMIC_RELEASE, "workgroup");
            __syncthreads();
        }
        lo = hi;
    }
    #undef OFFS
}

__global__ void k_out(const unsigned short* __restrict__ Hb, const float* __restrict__ C,
                      const int* __restrict__ idx, float* __restrict__ out) {
    const int b = blockIdx.x, t = threadIdx.x;
    if (b < NN) {
        int drow = idx[b];
        out[512 + (size_t)drow * DD + t] = bf2f(Hb[(size_t)b * DD + t]);
    } else {
        out[t] = C[t];
        out[DD + t] = bf2f(Hb[t]);
    }
}

extern "C" void kernel_launch(void* const* d_in, const int* in_sizes, int n_in,
                              void* d_out, int out_size, void* d_ws, size_t ws_size,
                              hipStream_t stream) {
    const float* X     = (const float*)d_in[0];
    const float* state = (const float*)d_in[1];
    const float* rootW = (const float*)d_in[2];
    const float* rootb = (const float*)d_in[3];
    const float* Wih   = (const float*)d_in[4];
    const float* Whh   = (const float*)d_in[5];
    const float* bih   = (const float*)d_in[6];
    const float* bhh   = (const float*)d_in[7];
    const int* parents = (const int*)d_in[8];
    const int* idx     = (const int*)d_in[9];

    float* C           = (float*)d_ws;                                   // 32 MiB
    unsigned short* Hb = (unsigned short*)(C + (size_t)NN * DD);         // 16 MiB
    unsigned short* Gp = Hb + (size_t)NN * DD;                           // 64 MiB
    int* ip            = (int*)(Gp + (size_t)NN * GP);
    int* depA = ip;            ip += NN;
    int* jmpA = ip;            ip += NN;
    int* depB = ip;            ip += NN;
    int* jmpB = ip;            ip += NN;
    int* cnt  = ip;            ip += NN + 2;
    int* off  = ip;            ip += NN + 2;
    int* cur  = ip;            ip += NN + 2;
    int* lev  = ip;            ip += NN;
    int* maxd = ip;            ip += 8;
    float* out = (float*)d_out;

    k_init_sched<<<dim3(129), dim3(256), 0, stream>>>(cnt, cur, maxd);
    k_dep_init<<<dim3(128), dim3(256), 0, stream>>>(parents, depA, jmpA);
    int* dA = depA; int* jA = jmpA; int* dB = depB; int* jB = jmpB;
    for (int it = 0; it < 15; ++it) {
        k_dep_step<<<dim3(128), dim3(256), 0, stream>>>(dA, jA, dB, jB);
        int* tp;
        tp = dA; dA = dB; dB = tp;
        tp = jA; jA = jB; jB = tp;
    }
    k_hist<<<dim3(128), dim3(256), 0, stream>>>(dA, cnt, maxd);
    k_scan<<<dim3(1), dim3(256), 0, stream>>>(cnt, off);
    k_scatter<<<dim3(128), dim3(256), 0, stream>>>(dA, off, cur, lev);

    k_gx<<<dim3(256), dim3(256), 0, stream>>>(X, Wih, bih, bhh, idx, Gp);

    k_poison<<<dim3(2048), dim3(256), 0, stream>>>(C, (unsigned*)Hb);
    k_root<<<dim3(1), dim3(256), 0, stream>>>(X, state, rootW, rootb, idx, Hb, C);
    k_tree2<<<dim3(256), dim3(256), 0, stream>>>(Whh, parents, off, lev, maxd, Gp, Hb, C);
    k_out<<<dim3(NN + 1), dim3(256), 0, stream>>>(Hb, C, idx, out);
}

// Round 9
// 2445.964 us; speedup vs baseline: 4.7852x; 1.1311x over previous
//
#include <hip/hip_runtime.h>

// TopDownTreeLSTM on MI355X — round 14: r8 + single machinery cut (R_s gone).
// r13 post-mortem: shfl id-distribution chains (~30 ds_permute/tile) + broken
// sentry cost +1us/hop; LDS broadcast is cheaper than shuffle chains. r14 is
// r8 byte-identical EXCEPT: W_hh staged per-wave (wave owns 8 hcols x 4
// gates, 2 B-tiles) so MFMA lands all gates in-lane; f/o via one shfl_xor(8)
// (r12/r13-verified math). Deletes R_s round trip + 1 barrier (5->4).
// Measured context (r10): maxd~1372, r8 hop 1.07us = 0.50 machinery + 0.57
// wait (~2 LLC RT floor). Pre-commit: result in [1420,1550] => roofline.

#define NN 32768
#define DD 256
#define GP 1024
#define OFFCAP 4096
#define SENT_C 0x7FC00001u   // f32 NaN payload: real c is always finite
#define SENT_H 0xFFFFFFFFu   // bf16 -NaN pair: real h in (-1,1)

typedef __attribute__((ext_vector_type(8))) short short8;
typedef __attribute__((ext_vector_type(4))) float float4_;
typedef __attribute__((ext_vector_type(4))) unsigned uint4_;

#define ATL(p) __hip_atomic_load((p), __ATOMIC_RELAXED, __HIP_MEMORY_SCOPE_AGENT)
#define ATS(p, v) __hip_atomic_store((p), (v), __ATOMIC_RELAXED, __HIP_MEMORY_SCOPE_AGENT)

static __device__ __forceinline__ unsigned short f2bf(float f) {
    unsigned u = __builtin_bit_cast(unsigned, f);
    unsigned r = u + 0x7FFFu + ((u >> 16) & 1u);
    return (unsigned short)(r >> 16);
}
static __device__ __forceinline__ float bf2f(unsigned short u) {
    unsigned v = ((unsigned)u) << 16;
    return __builtin_bit_cast(float, v);
}
static __device__ __forceinline__ float sigf(float x) { return 1.0f / (1.0f + __expf(-x)); }
static __device__ __forceinline__ float tanh_(float x) { return 1.0f - 2.0f / (__expf(2.0f * x) + 1.0f); }

__global__ void k_init_sched(int* cnt, int* cur, int* maxd) {
    int g = blockIdx.x * 256 + threadIdx.x;
    if (g < NN + 2) { cnt[g] = 0; cur[g] = 0; }
    if (g == 0) maxd[0] = 0;
}

// Poison C (f32 NaN) and Hb (bf16 -NaN pairs). Grid 2048 x 256.
__global__ void k_poison(float* C, unsigned* HbU) {
    const int g = blockIdx.x * 256 + threadIdx.x;
    const uint4_ sc = (uint4_){SENT_C, SENT_C, SENT_C, SENT_C};
    const uint4_ sh = (uint4_){SENT_H, SENT_H, SENT_H, SENT_H};
    uint4_* Cu = (uint4_*)C;
    uint4_* Hu = (uint4_*)HbU;
    #pragma unroll
    for (int k = 0; k < 4; ++k) Cu[(size_t)g + (size_t)k * 524288] = sc;
    #pragma unroll
    for (int k = 0; k < 2; ++k) Hu[(size_t)g + (size_t)k * 524288] = sh;
}

__global__ void k_root(const float* __restrict__ X, const float* __restrict__ state,
                       const float* __restrict__ rootW, const float* __restrict__ rootb,
                       const int* __restrict__ idx,
                       unsigned short* __restrict__ Hb, float* __restrict__ C) {
    const int t = threadIdx.x;
    const int row = idx[0];
    const float4_* xr = (const float4_*)(X + (size_t)row * DD);
    const float4_* wr = (const float4_*)(rootW + (size_t)t * DD);
    float acc = rootb[t];
    for (int k = 0; k < DD / 4; ++k) {
        float4_ a = xr[k], b = wr[k];
        acc += a[0] * b[0] + a[1] * b[1] + a[2] * b[2] + a[3] * b[3];
    }
    Hb[t] = f2bf(tanh_(acc));
    C[t] = state[t];
}

__global__ void k_dep_init(const int* __restrict__ parents, int* dep, int* jmp) {
    int i = blockIdx.x * 256 + threadIdx.x;
    if (i >= NN) return;
    dep[i] = (i == 0) ? 0 : 1;
    jmp[i] = (i == 0) ? 0 : parents[i];
}

__global__ void k_dep_step(const int* __restrict__ depA, const int* __restrict__ jmpA,
                           int* __restrict__ depB, int* __restrict__ jmpB) {
    int i = blockIdx.x * 256 + threadIdx.x;
    if (i >= NN) return;
    int j = jmpA[i];
    depB[i] = depA[i] + depA[j];
    jmpB[i] = jmpA[j];
}

__global__ void k_hist(const int* __restrict__ dep, int* cnt, int* maxd) {
    int i = blockIdx.x * 256 + threadIdx.x;
    if (i >= NN) return;
    int d = dep[i];
    atomicAdd(&cnt[d], 1);
    atomicMax(&maxd[0], d);
}

__global__ void k_scan(const int* __restrict__ cnt, int* __restrict__ off) {
    __shared__ int sums[256];
    const int tid = threadIdx.x;
    const int base = tid * 128;
    int s = 0;
    for (int k = 0; k < 128; ++k) s += cnt[base + k];
    sums[tid] = s;
    __syncthreads();
    if (tid == 0) {
        int run = 0;
        for (int t = 0; t < 256; ++t) { int tmp = sums[t]; sums[t] = run; run += tmp; }
    }
    __syncthreads();
    int run = sums[tid];
    for (int k = 0; k < 128; ++k) { off[base + k] = run; run += cnt[base + k]; }
    if (tid == 255) off[NN] = run;
}

__global__ void k_scatter(const int* __restrict__ dep, const int* __restrict__ off,
                          int* cur, int* __restrict__ lev) {
    int i = blockIdx.x * 256 + threadIdx.x;
    if (i >= NN) return;
    int d = dep[i];
    int pos = off[d] + atomicAdd(&cur[d], 1);
    lev[pos] = i;
}

// Throughput GEMM: Gpre[n][g] = X[idx[n]]·Wih[g] + bih[g] + bhh[g], bf16 out.
__global__ __launch_bounds__(256, 1) void k_gx(
    const float* __restrict__ X, const float* __restrict__ Wih,
    const float* __restrict__ bih, const float* __restrict__ bhh,
    const int* __restrict__ idx, unsigned short* __restrict__ Gp) {
    __shared__ __align__(16) short bw_s[128 * 264];
    __shared__ float bias_s[128];
    const int tid = threadIdx.x;
    const int w = tid >> 6, l = tid & 63;
    const int lanelo = l & 15, quad = l >> 4;

    short8 a[2][8];
    #pragma unroll
    for (int ti = 0; ti < 2; ++ti) {
        int n = (blockIdx.x * 8 + w * 2 + ti) * 16 + lanelo;
        int row = idx[n];
        const float* xp = X + (size_t)row * DD + quad * 8;
        #pragma unroll
        for (int ks = 0; ks < 8; ++ks) {
            float4_ x0 = *(const float4_*)(xp + ks * 32);
            float4_ x1 = *(const float4_*)(xp + ks * 32 + 4);
            short8 s;
            s[0] = f2bf(x0[0]); s[1] = f2bf(x0[1]); s[2] = f2bf(x0[2]); s[3] = f2bf(x0[3]);
            s[4] = f2bf(x1[0]); s[5] = f2bf(x1[1]); s[6] = f2bf(x1[2]); s[7] = f2bf(x1[3]);
            a[ti][ks] = s;
        }
    }
    for (int gc = 0; gc < 8; ++gc) {
        __syncthreads();
        for (int e = tid; e < 128 * 64; e += 256) {
            int r = e >> 6, c4 = (e & 63) * 4;
            float4_ b = *(const float4_*)(Wih + (size_t)(gc * 128 + r) * DD + c4);
            unsigned short* pb = (unsigned short*)&bw_s[r * 264 + c4];
            pb[0] = f2bf(b[0]); pb[1] = f2bf(b[1]); pb[2] = f2bf(b[2]); pb[3] = f2bf(b[3]);
        }
        if (tid < 128) bias_s[tid] = bih[gc * 128 + tid] + bhh[gc * 128 + tid];
        __syncthreads();
        #pragma unroll
        for (int ntl = 0; ntl < 8; ++ntl) {
            float4_ acc0 = (float4_){0.f, 0.f, 0.f, 0.f};
            float4_ acc1 = (float4_){0.f, 0.f, 0.f, 0.f};
            #pragma unroll
            for (int ks = 0; ks < 8; ++ks) {
                short8 bf = *(const short8*)&bw_s[(ntl * 16 + lanelo) * 264 + ks * 32 + quad * 8];
                acc0 = __builtin_amdgcn_mfma_f32_16x16x32_bf16(a[0][ks], bf, acc0, 0, 0, 0);
                acc1 = __builtin_amdgcn_mfma_f32_16x16x32_bf16(a[1][ks], bf, acc1, 0, 0, 0);
            }
            float bia = bias_s[ntl * 16 + lanelo];
            int g = gc * 128 + ntl * 16 + lanelo;
            int nb0 = (blockIdx.x * 8 + w * 2) * 16 + quad * 4;
            #pragma unroll
            for (int r = 0; r < 4; ++r) {
                Gp[(size_t)(nb0 + r) * GP + g] = f2bf(acc0[r] + bia);
                Gp[(size_t)(nb0 + 16 + r) * GP + g] = f2bf(acc1[r] + bia);
            }
        }
    }
}

// r8 skeleton; W per-wave layout; R_s deleted; gates resolved in-lane.
__global__ __launch_bounds__(256, 1) void k_tree2(
    const float* __restrict__ Whh,
    const int* __restrict__ parents,
    const int* __restrict__ off, const int* __restrict__ lev, const int* __restrict__ maxd_g,
    const unsigned short* __restrict__ Gp,
    unsigned short* __restrict__ Hb, float* __restrict__ C) {

    __shared__ __align__(16) short w_s[128 * 264];   // W_hh slice, per-wave tiles
    __shared__ __align__(16) short A_s[16 * 264];    // parent H rows, bf16
    __shared__ __align__(16) float G_s[16 * 128];    // Gpre tile (block's 128 gate cols)
    __shared__ int off_s[OFFCAP];                    // level offsets (LDS-rate)
    __shared__ int nd_s[16], par_s[16];

    const int tid = threadIdx.x;
    const int j = blockIdx.x & 7, grp = blockIdx.x >> 3;
    const int w = tid >> 6, l = tid & 63;
    const int lanelo = l & 15, quad = l >> 4;
    const bool ewl = (lanelo < 8);                   // elementwise-owner lanes
    const int colw = j * 32 + w * 8 + (lanelo & 7);  // ew lane's global hcol
    const int gcw = w * 8 + (lanelo & 7);            // within-block col (0..31)
    const int gof0 = (lanelo >> 3) * 32 + gcw;       // G_s col: i (lanes<8) / f
    const int gof1 = gof0 + 64;                      // G_s col: g / o

    // Stage W_hh per-wave: local row r = wp*32 + ti*16 + n ->
    // gate-row G = (ti*2 + (n>>3))*256 + j*32 + wp*8 + (n&7).
    for (int e = tid; e < 128 * 64; e += 256) {
        int r = e >> 6, c4 = (e & 63) * 4;
        int wp = r >> 5, ti = (r >> 4) & 1, n = r & 15;
        int G = (ti * 2 + (n >> 3)) * 256 + j * 32 + wp * 8 + (n & 7);
        float4_ b = *(const float4_*)(Whh + (size_t)G * DD + c4);
        unsigned short* pb = (unsigned short*)&w_s[r * 264 + c4];
        pb[0] = f2bf(b[0]); pb[1] = f2bf(b[1]); pb[2] = f2bf(b[2]); pb[3] = f2bf(b[3]);
    }
    const int maxd = maxd_g[0];
    const int staged = (maxd + 2 < OFFCAP) ? (maxd + 2) : OFFCAP;
    for (int e = tid; e < staged; e += 256) off_s[e] = off[e];
    __syncthreads();

    #define OFFS(i) (((i) < staged) ? off_s[(i)] : off[(i)])

    const unsigned* HbU = (const unsigned*)Hb;
    unsigned* HbW = (unsigned*)Hb;
    const unsigned* Cw = (const unsigned*)C;
    int pn_node = -1, pn_par = 0;
    bool pn_valid = false;

    int lo = OFFS(1);
    for (int d = 1; d <= maxd; ++d) {
        const int hi = OFFS(d + 1);
        const int tiles = (hi - lo + 15) >> 4;
        for (int t = grp; t < tiles; t += 32) {
            const int base = lo + t * 16;
            if (tid < 16) {
                if (pn_valid) {
                    nd_s[tid] = pn_node; par_s[tid] = pn_par;
                } else {
                    int node = -1, p = 0;
                    if (base + tid < hi) { node = lev[base + tid]; p = parents[node]; }
                    nd_s[tid] = node; par_s[tid] = p;
                }
            }
            pn_valid = false;
            __syncthreads();
            // G_s prefetch (r8 verbatim; static, no parent dependency).
            {
                int m = tid >> 4, q8 = (tid & 15) * 8;
                int seg = q8 >> 5, cc = q8 & 31;
                float4_ g01 = (float4_){0.f, 0.f, 0.f, 0.f};
                float4_ g23 = (float4_){0.f, 0.f, 0.f, 0.f};
                if (nd_s[m] >= 0) {
                    const unsigned short* gp =
                        Gp + (size_t)nd_s[m] * GP + seg * 256 + j * 32 + cc;
                    short8 gv = *(const short8*)gp;
                    g01[0] = bf2f(gv[0]); g01[1] = bf2f(gv[1]); g01[2] = bf2f(gv[2]); g01[3] = bf2f(gv[3]);
                    g23[0] = bf2f(gv[4]); g23[1] = bf2f(gv[5]); g23[2] = bf2f(gv[6]); g23[3] = bf2f(gv[7]);
                }
                *(float4_*)&G_s[m * 128 + q8] = g01;
                *(float4_*)&G_s[m * 128 + q8 + 4] = g23;
            }
            // Next-tile id prefetch (r8 verbatim).
            {
                int nt_base = -1, nt_hi = hi;
                if (t + 32 < tiles) {
                    nt_base = lo + (t + 32) * 16;
                } else if (d < maxd) {
                    const int hi2 = OFFS(d + 2);
                    const int tiles2 = (hi2 - hi + 15) >> 4;
                    if (grp < tiles2) { nt_base = hi + grp * 16; nt_hi = hi2; }
                }
                if (nt_base >= 0) {
                    if (tid < 16) {
                        int node = -1, p = 0;
                        if (nt_base + tid < nt_hi) { node = lev[nt_base + tid]; p = parents[node]; }
                        pn_node = node; pn_par = p;
                    }
                    pn_valid = true;
                }
            }
            // Volley: hv (r8 verbatim) + parent C for ew lanes.
            unsigned hv[8];
            bool ok = true;
            #pragma unroll
            for (int k2 = 0; k2 < 8; ++k2) {
                const int e = tid + k2 * 256, m = e >> 7, cu = e & 127;
                hv[k2] = (nd_s[m] >= 0)
                    ? ATL(&HbU[(size_t)par_s[m] * 128 + cu]) : 0u;
                if (nd_s[m] >= 0 && hv[k2] == SENT_H) ok = false;
            }
            unsigned cwv[4];
            #pragma unroll
            for (int r = 0; r < 4; ++r) {
                const int m = quad * 4 + r;
                cwv[r] = (ewl && nd_s[m] >= 0)
                    ? ATL(&Cw[(size_t)par_s[m] * DD + colw]) : 0u;
                if (ewl && nd_s[m] >= 0 && cwv[r] == SENT_C) ok = false;
            }
            if (!__syncthreads_and(ok ? 1 : 0)) {
                // Miss path (r8 verbatim): 16-lane block sentry on own j-slice,
                // then per-word revalidation.
                if (tid < 64) {
                    const int m = tid & 15;
                    const bool act = (tid < 16) && (nd_s[m] >= 0);
                    const unsigned* sp = &HbU[(size_t)par_s[m] * 128 + j * 16];
                    bool miss = act && (ATL(sp) == SENT_H);
                    while (__any(miss ? 1 : 0))
                        miss = act && (ATL(sp) == SENT_H);
                }
                __syncthreads();
                #pragma unroll
                for (int k2 = 0; k2 < 8; ++k2) {
                    const int e = tid + k2 * 256, m = e >> 7, cu = e & 127;
                    if (nd_s[m] >= 0)
                        while (hv[k2] == SENT_H) {
                            __builtin_amdgcn_s_sleep(1);
                            hv[k2] = ATL(&HbU[(size_t)par_s[m] * 128 + cu]);
                        }
                }
                #pragma unroll
                for (int r = 0; r < 4; ++r) {
                    const int m = quad * 4 + r;
                    if (ewl && nd_s[m] >= 0)
                        while (cwv[r] == SENT_C) {
                            __builtin_amdgcn_s_sleep(1);
                            cwv[r] = ATL(&Cw[(size_t)par_s[m] * DD + colw]);
                        }
                }
            }
            // Stage parent H into A_s (r8 verbatim).
            #pragma unroll
            for (int k2 = 0; k2 < 8; ++k2) {
                const int e = tid + k2 * 256, m = e >> 7, cu = e & 127;
                *(unsigned*)&A_s[m * 264 + cu * 2] = hv[k2];
            }
            __syncthreads();
            // MFMA: A from A_s; B = this wave's 2 tiles (i|f rows, g|o rows).
            float4_ acc0 = (float4_){0.f, 0.f, 0.f, 0.f};
            float4_ acc1 = (float4_){0.f, 0.f, 0.f, 0.f};
            {
                short8 af[8];
                #pragma unroll
                for (int ks = 0; ks < 8; ++ks)
                    af[ks] = *(const short8*)&A_s[lanelo * 264 + ks * 32 + quad * 8];
                #pragma unroll
                for (int ks = 0; ks < 8; ++ks) {
                    short8 b0 = *(const short8*)&w_s[(w * 32 + lanelo) * 264 + ks * 32 + quad * 8];
                    short8 b1 = *(const short8*)&w_s[(w * 32 + 16 + lanelo) * 264 + ks * 32 + quad * 8];
                    acc0 = __builtin_amdgcn_mfma_f32_16x16x32_bf16(af[ks], b0, acc0, 0, 0, 0);
                    acc1 = __builtin_amdgcn_mfma_f32_16x16x32_bf16(af[ks], b1, acc1, 0, 0, 0);
                }
            }
            // Elementwise in-lane: lanes<8 hold i|g, lanes 8-15 hold f|o for
            // the same cols -> one shfl_xor(8) per gate pair (verified math).
            #pragma unroll
            for (int r = 0; r < 4; ++r) {
                const int m = quad * 4 + r;
                float a0 = acc0[r] + G_s[m * 128 + gof0];   // i | f
                float a1 = acc1[r] + G_s[m * 128 + gof1];   // g | o
                float fg = __shfl_xor(a0, 8);
                float og = __shfl_xor(a1, 8);
                float cp = __builtin_bit_cast(float, cwv[r]);
                float cn = sigf(fg) * cp + sigf(a0) * tanh_(a1);
                float hn = sigf(og) * tanh_(cn);
                unsigned short hs = f2bf(hn);
                unsigned pair = ((unsigned)hs) |
                                (((unsigned)(unsigned short)__shfl_down((int)hs, 1)) << 16);
                if (ewl && nd_s[m] >= 0) {
                    ATS(&C[(size_t)nd_s[m] * DD + colw], cn);
                    if ((lanelo & 1) == 0)
                        ATS(&HbW[(size_t)nd_s[m] * 128 + (colw >> 1)], pair);
                }
            }
            // Drain to coherence point; final barrier protects A_s/G_s/nd_s.
            __builtin_amdgcn_fence(__ATOMIC_RELEASE, "workgroup");
            __syncthreads();
        }
        lo = hi;
    }
    #undef OFFS
}

__global__ void k_out(const unsigned short* __restrict__ Hb, const float* __restrict__ C,
                      const int* __restrict__ idx, float* __restrict__ out) {
    const int b = blockIdx.x, t = threadIdx.x;
    if (b < NN) {
        int drow = idx[b];
        out[512 + (size_t)drow * DD + t] = bf2f(Hb[(size_t)b * DD + t]);
    } else {
        out[t] = C[t];
        out[DD + t] = bf2f(Hb[t]);
    }
}

extern "C" void kernel_launch(void* const* d_in, const int* in_sizes, int n_in,
                              void* d_out, int out_size, void* d_ws, size_t ws_size,
                              hipStream_t stream) {
    const float* X     = (const float*)d_in[0];
    const float* state = (const float*)d_in[1];
    const float* rootW = (const float*)d_in[2];
    const float* rootb = (const float*)d_in[3];
    const float* Wih   = (const float*)d_in[4];
    const float* Whh   = (const float*)d_in[5];
    const float* bih   = (const float*)d_in[6];
    const float* bhh   = (const float*)d_in[7];
    const int* parents = (const int*)d_in[8];
    const int* idx     = (const int*)d_in[9];

    float* C           = (float*)d_ws;                                   // 32 MiB
    unsigned short* Hb = (unsigned short*)(C + (size_t)NN * DD);         // 16 MiB
    unsigned short* Gp = Hb + (size_t)NN * DD;                           // 64 MiB
    int* ip            = (int*)(Gp + (size_t)NN * GP);
    int* depA = ip;            ip += NN;
    int* jmpA = ip;            ip += NN;
    int* depB = ip;            ip += NN;
    int* jmpB = ip;            ip += NN;
    int* cnt  = ip;            ip += NN + 2;
    int* off  = ip;            ip += NN + 2;
    int* cur  = ip;            ip += NN + 2;
    int* lev  = ip;            ip += NN;
    int* maxd = ip;            ip += 8;
    float* out = (float*)d_out;

    k_init_sched<<<dim3(129), dim3(256), 0, stream>>>(cnt, cur, maxd);
    k_dep_init<<<dim3(128), dim3(256), 0, stream>>>(parents, depA, jmpA);
    int* dA = depA; int* jA = jmpA; int* dB = depB; int* jB = jmpB;
    for (int it = 0; it < 15; ++it) {
        k_dep_step<<<dim3(128), dim3(256), 0, stream>>>(dA, jA, dB, jB);
        int* tp;
        tp = dA; dA = dB; dB = tp;
        tp = jA; jA = jB; jB = tp;
    }
    k_hist<<<dim3(128), dim3(256), 0, stream>>>(dA, cnt, maxd);
    k_scan<<<dim3(1), dim3(256), 0, stream>>>(cnt, off);
    k_scatter<<<dim3(128), dim3(256), 0, stream>>>(dA, off, cur, lev);

    k_gx<<<dim3(256), dim3(256), 0, stream>>>(X, Wih, bih, bhh, idx, Gp);

    k_poison<<<dim3(2048), dim3(256), 0, stream>>>(C, (unsigned*)Hb);
    k_root<<<dim3(1), dim3(256), 0, stream>>>(X, state, rootW, rootb, idx, Hb, C);
    k_tree2<<<dim3(256), dim3(256), 0, stream>>>(Whh, parents, off, lev, maxd, Gp, Hb, C);
    k_out<<<dim3(NN + 1), dim3(256), 0, stream>>>(Hb, C, idx, out);
}